// Round 16
// baseline (35.238 us; speedup 1.0000x reference)
//
#include <hip/hip_runtime.h>
#include <cstdint>

typedef unsigned long long u64;
typedef __attribute__((ext_vector_type(8))) _Float16 half8;  // 8 f16 = 4 VGPR
typedef __attribute__((ext_vector_type(4))) float f32x4;

#define RFL(x) __builtin_amdgcn_readfirstlane(x)

__device__ __forceinline__ void gload_lds16(const void* g, void* l) {
    __builtin_amdgcn_global_load_lds(
        (const __attribute__((address_space(1))) unsigned int*)g,
        (__attribute__((address_space(3))) unsigned int*)l, 16, 0, 0);
}

// Dims: B=2, S=1024, C=512, H=8, hd=64, T=4.
// bits: [3][4(t)][2(b)][8(h)][1024(s)] u64  (bit d = channel)
// ws: bits 1.5M | (unused 0.5M) | xh 2M | xl 2M | wh 1.5M | csbuf 16K | flags 2K
// GEMM numerics (same as R13/R15): y ~= xh@wh + xl@wh (asymmetric fp16 split).

// ---------------- Kernel C (R15 verbatim): f32 -> {xh,xl,wh}; blk 896 zeroes aux.
__global__ __launch_bounds__(256) void cvt_split16(
    const float* __restrict__ x,
    const float* __restrict__ Wq, const float* __restrict__ Wk,
    const float* __restrict__ Wv,
    _Float16* __restrict__ xh, _Float16* __restrict__ xl,
    _Float16* __restrict__ wh,
    unsigned* __restrict__ csbuf)
{
    const int bid = blockIdx.x;
    if (bid == 896) {           // zero csbuf (4096 u32) + flags (512 u32)
#pragma unroll
        for (int i = 0; i < 18; ++i) {
            const int idx = i * 256 + threadIdx.x;
            if (idx < 4608) csbuf[idx] = 0u;
        }
        return;
    }
    if (bid < 512) {            // x: split
        const size_t j = (size_t)bid * 2048 + (size_t)threadIdx.x * 8;
        const float4 a = *(const float4*)(x + j);
        const float4 b = *(const float4*)(x + j + 4);
        const float va[8] = {a.x, a.y, a.z, a.w, b.x, b.y, b.z, b.w};
        half8 h8, l8;
#pragma unroll
        for (int i = 0; i < 8; ++i) {
            const _Float16 hi = (_Float16)va[i];          // RNE
            h8[i] = hi;
            l8[i] = (_Float16)(va[i] - (float)hi);
        }
        *(half8*)(xh + j) = h8;
        *(half8*)(xl + j) = l8;
    } else {                    // W: single fp16
        const size_t j = (size_t)(bid - 512) * 2048 + (size_t)threadIdx.x * 8;
        const int mat = (int)(j >> 18);           // 512*512 elems per matrix
        const size_t off = j & 262143;
        const float* s = ((mat == 0) ? Wq : (mat == 1) ? Wk : Wv) + off;
        const float4 a = *(const float4*)s;
        const float4 b = *(const float4*)(s + 4);
        const float va[8] = {a.x, a.y, a.z, a.w, b.x, b.y, b.z, b.w};
        half8 h8;
#pragma unroll
        for (int i = 0; i < 8; ++i) h8[i] = (_Float16)va[i];
        *(half8*)(wh + j) = h8;
    }
}

// ---------------- MFMA GEMM v8: 64x128 block tile (2 heads), wave = 32x64
// (acc[2][4]). Per kk: 8 ds_read_b128 feed 16 MFMA (R15 was 6:8) ->
// per-output LDS traffic and barrier count both halved. Grid 12x32 = 384
// blocks (>256 CUs), 64KB dbuf -> 2 blocks/CU. Per-acc MFMA chain
// (k ascending, hh->hl) operand-identical to R13/R15 -> y bitwise identical
// -> absmax tripwire 9.765625e-4. Flags (mat==0) and cs (mat==2) fused.
#define AH_OFF 0
#define AL_OFF 8192
#define BH_OFF 16384
#define BUF_STRIDE 32768

__global__ __launch_bounds__(256) void gemm_mfma_lif_pack8(
    const _Float16* __restrict__ xh, const _Float16* __restrict__ xl,
    const _Float16* __restrict__ wh,
    u64* __restrict__ bits,
    unsigned* __restrict__ csbuf,
    u64* __restrict__ flags)
{
    __shared__ __align__(16) char smem[65536];   // 2x32KB dbuf; epi 64*130*4

    const int tid  = threadIdx.x;
    const int lane = tid & 63;
    const int wv   = RFL(tid >> 6);
    const int byn2 = blockIdx.x;    // 12 = 3 mat * 4 head-pairs (FAST, XCD pin)
    const int bx   = blockIdx.y;    // 32 row tiles of 64
    const int mat = byn2 >> 2, hp = byn2 & 3;
    const int h2  = hp * 2;                       // first head of the pair
    const int wrow0 = mat * 512 + hp * 128;       // W concat row base

    const int wm = wv >> 1, wn = wv & 1;
    const int lg = lane >> 4, lr = lane & 15;

    const int lrow8 = lane >> 3;                  // row within 8-row stripe
    const int koff  = ((lane & 7) ^ lrow8) * 8;   // pre-swizzled global k-off

    f32x4 acc[2][4];
#pragma unroll
    for (int i = 0; i < 2; ++i)
#pragma unroll
        for (int j = 0; j < 4; ++j) acc[i][j] = (f32x4){0.f, 0.f, 0.f, 0.f};

#define STAGE(buf, k0)                                                        \
    {                                                                         \
        const int base_ = (buf) * BUF_STRIDE;                                 \
        _Pragma("unroll")                                                     \
        for (int sp = 0; sp < 2; ++sp) {          /* x: 8 stripes of 8 rows */\
            const int stripe = wv * 2 + sp;                                   \
            const int row = stripe * 8 + lrow8;                               \
            const size_t aoff = (size_t)(bx * 64 + row) * 512 + (k0) + koff;  \
            gload_lds16(xh + aoff, smem + base_ + AH_OFF + stripe * 1024);    \
            gload_lds16(xl + aoff, smem + base_ + AL_OFF + stripe * 1024);    \
        }                                                                     \
        _Pragma("unroll")                                                     \
        for (int sq = 0; sq < 4; ++sq) {          /* W: 16 stripes of 8 rows*/\
            const int stripe = wv * 4 + sq;                                   \
            const int row = stripe * 8 + lrow8;                               \
            const size_t boff = (size_t)(wrow0 + row) * 512 + (k0) + koff;    \
            gload_lds16(wh + boff, smem + base_ + BH_OFF + stripe * 1024);    \
        }                                                                     \
    }

    STAGE(0, 0);
    __syncthreads();

    for (int it = 0; it < 8; ++it) {
        const int cur = it & 1;
        if (it < 7) STAGE(cur ^ 1, (it + 1) * 64);

        const int base = cur * BUF_STRIDE;
#pragma unroll
        for (int kk = 0; kk < 64; kk += 32) {
            const int slotb = (kk >> 3) + lg;
            half8 ah[2], al[2], bh2[4];
#pragma unroll
            for (int fm = 0; fm < 2; ++fm) {
                const int row = wm * 32 + fm * 16 + lr;
                const int off = base + row * 128 + ((slotb ^ (row & 7)) << 4);
                ah[fm] = *(const half8*)(smem + AH_OFF + off);
                al[fm] = *(const half8*)(smem + AL_OFF + off);
            }
#pragma unroll
            for (int fn = 0; fn < 4; ++fn) {
                const int row = wn * 64 + fn * 16 + lr;
                const int off = base + row * 128 + ((slotb ^ (row & 7)) << 4);
                bh2[fn] = *(const half8*)(smem + BH_OFF + off);
            }
#pragma unroll
            for (int fm = 0; fm < 2; ++fm)
#pragma unroll
                for (int fn = 0; fn < 4; ++fn) {
                    acc[fm][fn] = __builtin_amdgcn_mfma_f32_16x16x32_f16(
                        ah[fm], bh2[fn], acc[fm][fn], 0, 0, 0);
                    acc[fm][fn] = __builtin_amdgcn_mfma_f32_16x16x32_f16(
                        al[fm], bh2[fn], acc[fm][fn], 0, 0, 0);
                }
        }
        __syncthreads();
    }
#undef STAGE

    // ---- epilogue: y tile -> LDS f32 [64][130], LIF + pack + flags + cs.
    float* yl = (float*)smem;
#pragma unroll
    for (int fm = 0; fm < 2; ++fm)
#pragma unroll
        for (int fn = 0; fn < 4; ++fn)
#pragma unroll
            for (int reg = 0; reg < 4; ++reg) {
                const int m_loc = wm * 32 + fm * 16 + lg * 4 + reg;  // row=(lane>>4)*4+reg
                const int n_loc = wn * 64 + fn * 16 + lr;            // col=lane&15
                yl[m_loc * 130 + n_loc] = acc[fm][fn][reg];
            }
    __syncthreads();

    int pcnt[2][4];
#pragma unroll
    for (int hh = 0; hh < 2; ++hh)
#pragma unroll
        for (int t = 0; t < 4; ++t) pcnt[hh][t] = 0;
    u64 flagbits[2] = {0, 0};

    for (int r = 0; r < 16; ++r) {
        const int lrow = wv * 16 + r;
        const int grow = bx * 64 + lrow;
        const int bb = grow >> 10;
        const int ss = grow & 1023;
#pragma unroll
        for (int hh = 0; hh < 2; ++hh) {
            const float y = yl[lrow * 130 + hh * 64 + lane];
            float v = 0.f;
            int sp[4];
#pragma unroll
            for (int t = 0; t < 4; ++t) {
                v = v + (y - v) * 0.5f;           // decay_input charge, tau=2
                const int s = (v - 1.0f >= 0.f) ? 1 : 0;
                v = s ? 0.f : v;                  // hard reset
                sp[t] = s;
                pcnt[hh][t] += s;
            }
            u64* dst = bits + (((size_t)(mat * 4) * 2 + bb) * 8 + (h2 + hh)) * 1024 + ss;
            u64 mskarr[4];
#pragma unroll
            for (int t = 0; t < 4; ++t) {
                const u64 msk = __ballot(sp[t]);
                mskarr[t] = msk;
                if (lane == 0) dst[(size_t)t * (2 * 8 * 1024)] = msk;
            }
            if (mat == 0) {         // level-1 screen (same recurrence as attn)
                const int cc0 = (int)__popcll(mskarr[0]);
                const int cc1 = (int)__popcll(mskarr[1]);
                const int cc2 = (int)__popcll(mskarr[2]);
                const int cc3 = (int)__popcll(mskarr[3]);
                unsigned B = (unsigned)(cc0 << 2);
                unsigned mB = B;
                B = (B >> 1) + (unsigned)(cc1 << 2); mB = max(mB, B);
                B = (B >> 1) + (unsigned)(cc2 << 2); mB = max(mB, B);
                B = (B >> 1) + (unsigned)(cc3 << 2); mB = max(mB, B);
                if (mB >= 64u) flagbits[hh] |= (1ull << lrow);
            }
        }
    }
    const int bb = (bx * 64) >> 10;
    if (mat == 2) {                 // cs accumulation (device-scope, exact)
#pragma unroll
        for (int hh = 0; hh < 2; ++hh) {
            const int bh = bb * 8 + h2 + hh;
#pragma unroll
            for (int t = 0; t < 4; ++t)
                atomicAdd(&csbuf[bh * 256 + t * 64 + lane], (unsigned)pcnt[hh][t]);
        }
    }
    if (mat == 0 && lane == 0) {
#pragma unroll
        for (int hh = 0; hh < 2; ++hh)
            if (flagbits[hh])
                atomicOr(&flags[(bb * 8 + h2 + hh) * 16 + (bx & 15)], flagbits[hh]);
    }
}

// ---------------- Kernel B10 (R15 verbatim): flag-gated attn.
__global__ __launch_bounds__(256) void spike_attn10(
    const u64* __restrict__ bits,
    const unsigned* __restrict__ csbuf,
    const u64* __restrict__ flags,
    float* __restrict__ out)
{
    __shared__ u64 kb_s[4][1024];   // 32 KiB

    const int lane = threadIdx.x & 63;
    const int wave = RFL((int)(threadIdx.x >> 6));
    const int rt = blockIdx.x;   // 64 tiles of 16 rows
    const int h  = blockIdx.y;
    const int b  = blockIdx.z;

    const int bh = b * 8 + h;
    const u64* __restrict__ qb = bits + (size_t)bh * 1024;         // + t*16384
    const u64* __restrict__ kb = bits + (size_t)(64 + bh) * 1024;  // + t*16384
    const u64* __restrict__ vb = bits + (size_t)(128 + bh) * 1024; // + t*16384

    {
        const u64* __restrict__ srcT = kb + (size_t)wave * 16384;
#pragma unroll
        for (int i = 0; i < 8; ++i)
            gload_lds16(srcT + i * 128 + lane * 2, &kb_s[wave][i * 128]);
    }

    int cs[4];
#pragma unroll
    for (int t = 0; t < 4; ++t)
        cs[t] = (int)csbuf[bh * 256 + t * 64 + lane];
    const float base = (float)(cs[0] + cs[1] + cs[2] + cs[3]) * (1.0f / 4096.0f);

    const int s0 = rt * 16 + wave * 4;      // 4 rows per wave
    const u64 flagw = flags[bh * 16 + (s0 >> 6)];

    __syncthreads();   // kb_s ready

    const float E1 = 0.36787944117144233f;  // expf(-1)

#pragma unroll
    for (int r = 0; r < 4; ++r) {
        const int s = s0 + r;
        float o = base;
        if ((flagw >> (s & 63)) & 1ull) {   // wave-uniform; ~15-20% of rows
            const u64 q0 = qb[s];
            const u64 q1 = qb[16384 + s];
            const u64 q2 = qb[32768 + s];
            const u64 q3 = qb[49152 + s];
            int found = 0;
            for (int w = 0; w < 16; ++w) {
                const int ko = (w << 6) + lane;
                const int pc0 = (int)__popcll(kb_s[0][ko] & q0);
                const int pc1 = (int)__popcll(kb_s[1][ko] & q1);
                const int pc2 = (int)__popcll(kb_s[2][ko] & q2);
                const int pc3 = (int)__popcll(kb_s[3][ko] & q3);
                found = max(found, max(max(pc0, pc1), max(pc2, pc3)));
            }
            const u64 any = __ballot(found >= 9);
            if (any) {              // wave-uniform; rare
                int msum[4] = {0, 0, 0, 0}, n11[4] = {0, 0, 0, 0};
                for (int w = 0; w < 16; ++w) {
                    const int ko = (w << 6) + lane;
                    const int pcs[4] = {
                        (int)__popcll(kb_s[0][ko] & q0),
                        (int)__popcll(kb_s[1][ko] & q1),
                        (int)__popcll(kb_s[2][ko] & q2),
                        (int)__popcll(kb_s[3][ko] & q3)};
                    unsigned u = 0;
#pragma unroll
                    for (int t = 0; t < 4; ++t) {
                        u = (u >> 1) + (unsigned)(pcs[t] << 2);  // 64ths; exact
                        const int spk = (u >= 64u) ? 1 : 0;
                        const u64 msk = __ballot(spk);
                        u = spk ? 0u : u;
                        msum[t] += (int)__popcll(msk);
                        u64 m = msk;
                        while (m) {     // bit-scan: 1 broadcast v-load/spike
                            const int j = (int)__builtin_ctzll(m);
                            m &= m - 1;
                            const u64 vw = vb[t * 16384 + (w << 6) + j];
                            n11[t] += (int)((vw >> lane) & 1ull);
                        }
                    }
                }
                o = 0.f;
#pragma unroll
                for (int t = 0; t < 4; ++t) {
                    const float mf = (float)msum[t];
                    const float Z  = mf + (1024.f - mf) * E1;
                    const float p1 = 1.0f / Z;
                    const float p0 = E1 / Z;
                    o += p0 * (float)cs[t] + (p1 - p0) * (float)n11[t];
                }
                o *= 0.25f;
            }
        }
        out[((size_t)b * 1024 + s) * 512 + (h << 6) + lane] = o;
    }
}

extern "C" void kernel_launch(void* const* d_in, const int* in_sizes, int n_in,
                              void* d_out, int out_size, void* d_ws, size_t ws_size,
                              hipStream_t stream) {
    const float* x  = (const float*)d_in[0];
    const float* Wq = (const float*)d_in[1];
    const float* Wk = (const float*)d_in[2];
    const float* Wv = (const float*)d_in[3];
    float* out = (float*)d_out;

    u64* bits = (u64*)d_ws;                          // 1.5 MiB (+0.5 unused)
    _Float16* xh = (_Float16*)((char*)d_ws + (2u << 20));
    _Float16* xl = xh + (size_t)2048 * 512;
    _Float16* wh = xl + (size_t)2048 * 512;
    unsigned* csbuf = (unsigned*)(wh + (size_t)1536 * 512);  // 16 KiB
    u64* flags = (u64*)(csbuf + 4096);                       // 2 KiB

    cvt_split16<<<dim3(897), 256, 0, stream>>>(x, Wq, Wk, Wv, xh, xl, wh, csbuf);
    gemm_mfma_lif_pack8<<<dim3(12, 32), 256, 0, stream>>>(xh, xl, wh, bits, csbuf, flags);
    spike_attn10<<<dim3(64, 8, 2), 256, 0, stream>>>(bits, csbuf, flags, out);
}

// Round 17
// 33.920 us; speedup vs baseline: 1.0389x; 1.0389x over previous
//
#include <hip/hip_runtime.h>
#include <cstdint>

typedef unsigned long long u64;
typedef __attribute__((ext_vector_type(8))) _Float16 half8;  // 8 f16 = 4 VGPR
typedef __attribute__((ext_vector_type(4))) float f32x4;

#define RFL(x) __builtin_amdgcn_readfirstlane(x)

__device__ __forceinline__ void gload_lds16(const void* g, void* l) {
    __builtin_amdgcn_global_load_lds(
        (const __attribute__((address_space(1))) unsigned int*)g,
        (__attribute__((address_space(3))) unsigned int*)l, 16, 0, 0);
}

// Dims: B=2, S=1024, C=512, H=8, hd=64, T=4.
// bits: [3][4(t)][2(b)][8(h)][1024(s)] u64  (bit d = channel)
// ws: bits 1.5M | (unused 0.5M) | xh 2M | xl 2M | wh 1.5M | csbuf 16K | flags 2K
// GEMM numerics (same as R13/R15): y ~= xh@wh + xl@wh (asymmetric fp16 split).

// ---------------- Kernel C (R15 verbatim): f32 -> {xh,xl,wh}; blk 896 zeroes aux.
__global__ __launch_bounds__(256) void cvt_split16(
    const float* __restrict__ x,
    const float* __restrict__ Wq, const float* __restrict__ Wk,
    const float* __restrict__ Wv,
    _Float16* __restrict__ xh, _Float16* __restrict__ xl,
    _Float16* __restrict__ wh,
    unsigned* __restrict__ csbuf)
{
    const int bid = blockIdx.x;
    if (bid == 896) {           // zero csbuf (4096 u32) + flags (512 u32)
#pragma unroll
        for (int i = 0; i < 18; ++i) {
            const int idx = i * 256 + threadIdx.x;
            if (idx < 4608) csbuf[idx] = 0u;
        }
        return;
    }
    if (bid < 512) {            // x: split
        const size_t j = (size_t)bid * 2048 + (size_t)threadIdx.x * 8;
        const float4 a = *(const float4*)(x + j);
        const float4 b = *(const float4*)(x + j + 4);
        const float va[8] = {a.x, a.y, a.z, a.w, b.x, b.y, b.z, b.w};
        half8 h8, l8;
#pragma unroll
        for (int i = 0; i < 8; ++i) {
            const _Float16 hi = (_Float16)va[i];          // RNE
            h8[i] = hi;
            l8[i] = (_Float16)(va[i] - (float)hi);
        }
        *(half8*)(xh + j) = h8;
        *(half8*)(xl + j) = l8;
    } else {                    // W: single fp16
        const size_t j = (size_t)(bid - 512) * 2048 + (size_t)threadIdx.x * 8;
        const int mat = (int)(j >> 18);           // 512*512 elems per matrix
        const size_t off = j & 262143;
        const float* s = ((mat == 0) ? Wq : (mat == 1) ? Wk : Wv) + off;
        const float4 a = *(const float4*)s;
        const float4 b = *(const float4*)(s + 4);
        const float va[8] = {a.x, a.y, a.z, a.w, b.x, b.y, b.z, b.w};
        half8 h8;
#pragma unroll
        for (int i = 0; i < 8; ++i) h8[i] = (_Float16)va[i];
        *(half8*)(wh + j) = h8;
    }
}

// ---------------- MFMA GEMM v6 (R15 verbatim): fp16 2-pass, 64x64 tile,
// BK=64 dbuf, gload_lds staging, byn-fast grid (XCD L2 pinning), flags
// (mat==0) and cs (mat==2) fused. y bitwise identical -> absmax tripwire
// 9.765625e-4. [Tile-space probes R9/R14/R16 all regressed; this is the
// measured local optimum of the 2-barrier structure.]
#define AH_OFF 0
#define AL_OFF 8192
#define BH_OFF 16384
#define BUF_STRIDE 24576

__global__ __launch_bounds__(256) void gemm_mfma_lif_pack6(
    const _Float16* __restrict__ xh, const _Float16* __restrict__ xl,
    const _Float16* __restrict__ wh,
    u64* __restrict__ bits,
    unsigned* __restrict__ csbuf,
    u64* __restrict__ flags)
{
    __shared__ __align__(16) char smem[49152];

    const int tid  = threadIdx.x;
    const int lane = tid & 63;
    const int wv   = RFL(tid >> 6);
    const int byn = blockIdx.x;     // 24 = 3 mat * 8 heads  (FAST dim)
    const int bx  = blockIdx.y;     // 32 row tiles of 64
    const int mat = byn >> 3, h = byn & 7;

    const int wm = wv >> 1, wn = wv & 1;
    const int lg = lane >> 4, lr = lane & 15;

    const int lrow8 = lane >> 3;
    const int koff  = ((lane & 7) ^ lrow8) * 8;   // pre-swizzled global k-off

    f32x4 acc[2][2] = {{{0.f,0.f,0.f,0.f},{0.f,0.f,0.f,0.f}},
                       {{0.f,0.f,0.f,0.f},{0.f,0.f,0.f,0.f}}};

#define STAGE(buf, k0)                                                        \
    {                                                                         \
        const int base_ = (buf) * BUF_STRIDE;                                 \
        _Pragma("unroll")                                                     \
        for (int sp = 0; sp < 2; ++sp) {                                      \
            const int stripe = wv * 2 + sp;                                   \
            const int row = stripe * 8 + lrow8;                               \
            const size_t aoff = (size_t)(bx * 64 + row) * 512 + (k0) + koff;  \
            const size_t boff = (size_t)(byn * 64 + row) * 512 + (k0) + koff; \
            gload_lds16(xh + aoff, smem + base_ + AH_OFF + stripe * 1024);    \
            gload_lds16(xl + aoff, smem + base_ + AL_OFF + stripe * 1024);    \
            gload_lds16(wh + boff, smem + base_ + BH_OFF + stripe * 1024);    \
        }                                                                     \
    }

    STAGE(0, 0);
    __syncthreads();

    for (int it = 0; it < 8; ++it) {
        const int cur = it & 1;
        if (it < 7) STAGE(cur ^ 1, (it + 1) * 64);

        const int base = cur * BUF_STRIDE;
#pragma unroll
        for (int kk = 0; kk < 64; kk += 32) {
            const int slotb = (kk >> 3) + lg;
            half8 ah[2], al[2], bh2[2];
#pragma unroll
            for (int fm = 0; fm < 2; ++fm) {
                const int row = wm * 32 + fm * 16 + lr;
                const int off = base + row * 128 + ((slotb ^ (row & 7)) << 4);
                ah[fm] = *(const half8*)(smem + AH_OFF + off);
                al[fm] = *(const half8*)(smem + AL_OFF + off);
            }
#pragma unroll
            for (int fn = 0; fn < 2; ++fn) {
                const int row = wn * 32 + fn * 16 + lr;
                const int off = base + row * 128 + ((slotb ^ (row & 7)) << 4);
                bh2[fn] = *(const half8*)(smem + BH_OFF + off);
            }
#pragma unroll
            for (int fm = 0; fm < 2; ++fm)
#pragma unroll
                for (int fn = 0; fn < 2; ++fn) {
                    acc[fm][fn] = __builtin_amdgcn_mfma_f32_16x16x32_f16(
                        ah[fm], bh2[fn], acc[fm][fn], 0, 0, 0);
                    acc[fm][fn] = __builtin_amdgcn_mfma_f32_16x16x32_f16(
                        al[fm], bh2[fn], acc[fm][fn], 0, 0, 0);
                }
        }
        __syncthreads();
    }
#undef STAGE

    float* yl = (float*)smem;
#pragma unroll
    for (int fm = 0; fm < 2; ++fm)
#pragma unroll
        for (int fn = 0; fn < 2; ++fn)
#pragma unroll
            for (int reg = 0; reg < 4; ++reg) {
                const int m_loc = wm * 32 + fm * 16 + lg * 4 + reg;  // row=(lane>>4)*4+reg
                const int n_loc = wn * 32 + fn * 16 + lr;            // col=lane&15
                yl[m_loc * 65 + n_loc] = acc[fm][fn][reg];
            }
    __syncthreads();

    int pcnt[4] = {0, 0, 0, 0};     // per-lane v-spike column partials
    u64 flagbits = 0;               // level-1 flags for this wave's 16 rows
    for (int r = 0; r < 16; ++r) {
        const int lrow = wv * 16 + r;
        const float y = yl[lrow * 65 + lane];
        float v = 0.f;
        int sp[4];
#pragma unroll
        for (int t = 0; t < 4; ++t) {
            v = v + (y - v) * 0.5f;           // decay_input charge, tau=2
            const int s = (v - 1.0f >= 0.f) ? 1 : 0;
            v = s ? 0.f : v;                  // hard reset
            sp[t] = s;
            pcnt[t] += s;
        }
        const int grow = bx * 64 + lrow;
        const int bb = grow >> 10;
        const int ss = grow & 1023;
        u64* dst = bits + (((size_t)(mat * 4) * 2 + bb) * 8 + h) * 1024 + ss;
        u64 mskarr[4];
#pragma unroll
        for (int t = 0; t < 4; ++t) {
            const u64 msk = __ballot(sp[t]);
            mskarr[t] = msk;
            if (lane == 0) dst[(size_t)t * (2 * 8 * 1024)] = msk;
        }
        if (mat == 0) {             // level-1 screen (same recurrence as attn)
            const int cc0 = (int)__popcll(mskarr[0]);
            const int cc1 = (int)__popcll(mskarr[1]);
            const int cc2 = (int)__popcll(mskarr[2]);
            const int cc3 = (int)__popcll(mskarr[3]);
            unsigned B = (unsigned)(cc0 << 2);
            unsigned mB = B;
            B = (B >> 1) + (unsigned)(cc1 << 2); mB = max(mB, B);
            B = (B >> 1) + (unsigned)(cc2 << 2); mB = max(mB, B);
            B = (B >> 1) + (unsigned)(cc3 << 2); mB = max(mB, B);
            if (mB >= 64u) flagbits |= (1ull << lrow);
        }
    }
    if (mat == 2) {                 // cs accumulation (device-scope, exact)
        const int bb = (bx * 64) >> 10;
        const int bh = bb * 8 + h;
#pragma unroll
        for (int t = 0; t < 4; ++t)
            atomicAdd(&csbuf[bh * 256 + t * 64 + lane], (unsigned)pcnt[t]);
    }
    if (mat == 0 && lane == 0 && flagbits) {
        const int bb = (bx * 64) >> 10;
        const int bh = bb * 8 + h;
        atomicOr(&flags[bh * 16 + (bx & 15)], flagbits);
    }
}

// ---------------- Kernel B11: flag-gated attn, staging amortized 2x.
// Grid (32,8,2): each block covers 32 rows (2 row-tiles looped), staging kb
// once -> kb staging redundancy x32 (was x64), still >=2 blocks/CU of TLP.
// All decisions bit-identical to R15.
__global__ __launch_bounds__(256) void spike_attn11(
    const u64* __restrict__ bits,
    const unsigned* __restrict__ csbuf,
    const u64* __restrict__ flags,
    float* __restrict__ out)
{
    __shared__ u64 kb_s[4][1024];   // 32 KiB

    const int lane = threadIdx.x & 63;
    const int wave = RFL((int)(threadIdx.x >> 6));
    const int rt = blockIdx.x;   // 32 tiles of 32 rows
    const int h  = blockIdx.y;
    const int b  = blockIdx.z;

    const int bh = b * 8 + h;
    const u64* __restrict__ qb = bits + (size_t)bh * 1024;         // + t*16384
    const u64* __restrict__ kb = bits + (size_t)(64 + bh) * 1024;  // + t*16384
    const u64* __restrict__ vb = bits + (size_t)(128 + bh) * 1024; // + t*16384

    {
        const u64* __restrict__ srcT = kb + (size_t)wave * 16384;
#pragma unroll
        for (int i = 0; i < 8; ++i)
            gload_lds16(srcT + i * 128 + lane * 2, &kb_s[wave][i * 128]);
    }

    int cs[4];
#pragma unroll
    for (int t = 0; t < 4; ++t)
        cs[t] = (int)csbuf[bh * 256 + t * 64 + lane];
    const float base = (float)(cs[0] + cs[1] + cs[2] + cs[3]) * (1.0f / 4096.0f);

    __syncthreads();   // kb_s ready

    const float E1 = 0.36787944117144233f;  // expf(-1)

    for (int ri = 0; ri < 2; ++ri) {
        const int s0 = rt * 32 + ri * 16 + wave * 4;   // 4 rows per wave
        const u64 flagw = flags[bh * 16 + (s0 >> 6)];

#pragma unroll
        for (int r = 0; r < 4; ++r) {
            const int s = s0 + r;
            float o = base;
            if ((flagw >> (s & 63)) & 1ull) {   // wave-uniform; ~15-20% of rows
                const u64 q0 = qb[s];
                const u64 q1 = qb[16384 + s];
                const u64 q2 = qb[32768 + s];
                const u64 q3 = qb[49152 + s];
                int found = 0;
                for (int w = 0; w < 16; ++w) {
                    const int ko = (w << 6) + lane;
                    const int pc0 = (int)__popcll(kb_s[0][ko] & q0);
                    const int pc1 = (int)__popcll(kb_s[1][ko] & q1);
                    const int pc2 = (int)__popcll(kb_s[2][ko] & q2);
                    const int pc3 = (int)__popcll(kb_s[3][ko] & q3);
                    found = max(found, max(max(pc0, pc1), max(pc2, pc3)));
                }
                const u64 any = __ballot(found >= 9);
                if (any) {              // wave-uniform; rare
                    int msum[4] = {0, 0, 0, 0}, n11[4] = {0, 0, 0, 0};
                    for (int w = 0; w < 16; ++w) {
                        const int ko = (w << 6) + lane;
                        const int pcs[4] = {
                            (int)__popcll(kb_s[0][ko] & q0),
                            (int)__popcll(kb_s[1][ko] & q1),
                            (int)__popcll(kb_s[2][ko] & q2),
                            (int)__popcll(kb_s[3][ko] & q3)};
                        unsigned u = 0;
#pragma unroll
                        for (int t = 0; t < 4; ++t) {
                            u = (u >> 1) + (unsigned)(pcs[t] << 2);  // exact
                            const int spk = (u >= 64u) ? 1 : 0;
                            const u64 msk = __ballot(spk);
                            u = spk ? 0u : u;
                            msum[t] += (int)__popcll(msk);
                            u64 m = msk;
                            while (m) {   // bit-scan: 1 broadcast v-load/spike
                                const int j = (int)__builtin_ctzll(m);
                                m &= m - 1;
                                const u64 vw = vb[t * 16384 + (w << 6) + j];
                                n11[t] += (int)((vw >> lane) & 1ull);
                            }
                        }
                    }
                    o = 0.f;
#pragma unroll
                    for (int t = 0; t < 4; ++t) {
                        const float mf = (float)msum[t];
                        const float Z  = mf + (1024.f - mf) * E1;
                        const float p1 = 1.0f / Z;
                        const float p0 = E1 / Z;
                        o += p0 * (float)cs[t] + (p1 - p0) * (float)n11[t];
                    }
                    o *= 0.25f;
                }
            }
            out[((size_t)b * 1024 + s) * 512 + (h << 6) + lane] = o;
        }
    }
}

extern "C" void kernel_launch(void* const* d_in, const int* in_sizes, int n_in,
                              void* d_out, int out_size, void* d_ws, size_t ws_size,
                              hipStream_t stream) {
    const float* x  = (const float*)d_in[0];
    const float* Wq = (const float*)d_in[1];
    const float* Wk = (const float*)d_in[2];
    const float* Wv = (const float*)d_in[3];
    float* out = (float*)d_out;

    u64* bits = (u64*)d_ws;                          // 1.5 MiB (+0.5 unused)
    _Float16* xh = (_Float16*)((char*)d_ws + (2u << 20));
    _Float16* xl = xh + (size_t)2048 * 512;
    _Float16* wh = xl + (size_t)2048 * 512;
    unsigned* csbuf = (unsigned*)(wh + (size_t)1536 * 512);  // 16 KiB
    u64* flags = (u64*)(csbuf + 4096);                       // 2 KiB

    cvt_split16<<<dim3(897), 256, 0, stream>>>(x, Wq, Wk, Wv, xh, xl, wh, csbuf);
    gemm_mfma_lif_pack6<<<dim3(24, 32), 256, 0, stream>>>(xh, xl, wh, bits, csbuf, flags);
    spike_attn11<<<dim3(32, 8, 2), 256, 0, stream>>>(bits, csbuf, flags, out);
}

// Round 18
// 32.676 us; speedup vs baseline: 1.0784x; 1.0381x over previous
//
#include <hip/hip_runtime.h>
#include <cstdint>

typedef unsigned long long u64;
typedef __attribute__((ext_vector_type(8))) _Float16 half8;  // 8 f16 = 4 VGPR
typedef __attribute__((ext_vector_type(4))) float f32x4;

#define RFL(x) __builtin_amdgcn_readfirstlane(x)

__device__ __forceinline__ void gload_lds16(const void* g, void* l) {
    __builtin_amdgcn_global_load_lds(
        (const __attribute__((address_space(1))) unsigned int*)g,
        (__attribute__((address_space(3))) unsigned int*)l, 16, 0, 0);
}

// Dims: B=2, S=1024, C=512, H=8, hd=64, T=4.
// bits: [3][4(t)][2(b)][8(h)][1024(s)] u64  (bit d = channel)
// ws: bits 1.5M | (unused 0.5M) | xh 2M | xl 2M | wh 1.5M | csbuf 16K | flags 2K
// GEMM numerics: y ~= xh@wh + xl@wh (asymmetric fp16 split; R13-verified).
// This file is the R15 configuration verbatim — best measured (32.8 us).

// ---------------- Kernel C: f32 -> {xh,xl,wh}; blk 896 zeroes csbuf+flags.
__global__ __launch_bounds__(256) void cvt_split16(
    const float* __restrict__ x,
    const float* __restrict__ Wq, const float* __restrict__ Wk,
    const float* __restrict__ Wv,
    _Float16* __restrict__ xh, _Float16* __restrict__ xl,
    _Float16* __restrict__ wh,
    unsigned* __restrict__ csbuf)
{
    const int bid = blockIdx.x;
    if (bid == 896) {           // zero csbuf (4096 u32) + flags (512 u32)
#pragma unroll
        for (int i = 0; i < 18; ++i) {
            const int idx = i * 256 + threadIdx.x;
            if (idx < 4608) csbuf[idx] = 0u;
        }
        return;
    }
    if (bid < 512) {            // x: split
        const size_t j = (size_t)bid * 2048 + (size_t)threadIdx.x * 8;
        const float4 a = *(const float4*)(x + j);
        const float4 b = *(const float4*)(x + j + 4);
        const float va[8] = {a.x, a.y, a.z, a.w, b.x, b.y, b.z, b.w};
        half8 h8, l8;
#pragma unroll
        for (int i = 0; i < 8; ++i) {
            const _Float16 hi = (_Float16)va[i];          // RNE
            h8[i] = hi;
            l8[i] = (_Float16)(va[i] - (float)hi);
        }
        *(half8*)(xh + j) = h8;
        *(half8*)(xl + j) = l8;
    } else {                    // W: single fp16
        const size_t j = (size_t)(bid - 512) * 2048 + (size_t)threadIdx.x * 8;
        const int mat = (int)(j >> 18);           // 512*512 elems per matrix
        const size_t off = j & 262143;
        const float* s = ((mat == 0) ? Wq : (mat == 1) ? Wk : Wv) + off;
        const float4 a = *(const float4*)s;
        const float4 b = *(const float4*)(s + 4);
        const float va[8] = {a.x, a.y, a.z, a.w, b.x, b.y, b.z, b.w};
        half8 h8;
#pragma unroll
        for (int i = 0; i < 8; ++i) h8[i] = (_Float16)va[i];
        *(half8*)(wh + j) = h8;
    }
}

// ---------------- MFMA GEMM v6: fp16 2-pass, 64x64 tile, BK=64 dbuf,
// gload_lds staging, byn-fast grid (XCD L2 pinning), flags (mat==0) and
// cs (mat==2) fused. Measured local optimum of the 2-barrier structure
// (R9 128^2, R14 BK=32, R16 64x128 all regressed). absmax tripwire
// 9.765625e-4 (y bitwise-stable since R13).
#define AH_OFF 0
#define AL_OFF 8192
#define BH_OFF 16384
#define BUF_STRIDE 24576

__global__ __launch_bounds__(256) void gemm_mfma_lif_pack6(
    const _Float16* __restrict__ xh, const _Float16* __restrict__ xl,
    const _Float16* __restrict__ wh,
    u64* __restrict__ bits,
    unsigned* __restrict__ csbuf,
    u64* __restrict__ flags)
{
    __shared__ __align__(16) char smem[49152];

    const int tid  = threadIdx.x;
    const int lane = tid & 63;
    const int wv   = RFL(tid >> 6);
    const int byn = blockIdx.x;     // 24 = 3 mat * 8 heads  (FAST dim)
    const int bx  = blockIdx.y;     // 32 row tiles of 64
    const int mat = byn >> 3, h = byn & 7;

    const int wm = wv >> 1, wn = wv & 1;
    const int lg = lane >> 4, lr = lane & 15;

    const int lrow8 = lane >> 3;
    const int koff  = ((lane & 7) ^ lrow8) * 8;   // pre-swizzled global k-off

    f32x4 acc[2][2] = {{{0.f,0.f,0.f,0.f},{0.f,0.f,0.f,0.f}},
                       {{0.f,0.f,0.f,0.f},{0.f,0.f,0.f,0.f}}};

#define STAGE(buf, k0)                                                        \
    {                                                                         \
        const int base_ = (buf) * BUF_STRIDE;                                 \
        _Pragma("unroll")                                                     \
        for (int sp = 0; sp < 2; ++sp) {                                      \
            const int stripe = wv * 2 + sp;                                   \
            const int row = stripe * 8 + lrow8;                               \
            const size_t aoff = (size_t)(bx * 64 + row) * 512 + (k0) + koff;  \
            const size_t boff = (size_t)(byn * 64 + row) * 512 + (k0) + koff; \
            gload_lds16(xh + aoff, smem + base_ + AH_OFF + stripe * 1024);    \
            gload_lds16(xl + aoff, smem + base_ + AL_OFF + stripe * 1024);    \
            gload_lds16(wh + boff, smem + base_ + BH_OFF + stripe * 1024);    \
        }                                                                     \
    }

    STAGE(0, 0);
    __syncthreads();

    for (int it = 0; it < 8; ++it) {
        const int cur = it & 1;
        if (it < 7) STAGE(cur ^ 1, (it + 1) * 64);

        const int base = cur * BUF_STRIDE;
#pragma unroll
        for (int kk = 0; kk < 64; kk += 32) {
            const int slotb = (kk >> 3) + lg;
            half8 ah[2], al[2], bh2[2];
#pragma unroll
            for (int fm = 0; fm < 2; ++fm) {
                const int row = wm * 32 + fm * 16 + lr;
                const int off = base + row * 128 + ((slotb ^ (row & 7)) << 4);
                ah[fm] = *(const half8*)(smem + AH_OFF + off);
                al[fm] = *(const half8*)(smem + AL_OFF + off);
            }
#pragma unroll
            for (int fn = 0; fn < 2; ++fn) {
                const int row = wn * 32 + fn * 16 + lr;
                const int off = base + row * 128 + ((slotb ^ (row & 7)) << 4);
                bh2[fn] = *(const half8*)(smem + BH_OFF + off);
            }
#pragma unroll
            for (int fm = 0; fm < 2; ++fm)
#pragma unroll
                for (int fn = 0; fn < 2; ++fn) {
                    acc[fm][fn] = __builtin_amdgcn_mfma_f32_16x16x32_f16(
                        ah[fm], bh2[fn], acc[fm][fn], 0, 0, 0);
                    acc[fm][fn] = __builtin_amdgcn_mfma_f32_16x16x32_f16(
                        al[fm], bh2[fn], acc[fm][fn], 0, 0, 0);
                }
        }
        __syncthreads();
    }
#undef STAGE

    float* yl = (float*)smem;
#pragma unroll
    for (int fm = 0; fm < 2; ++fm)
#pragma unroll
        for (int fn = 0; fn < 2; ++fn)
#pragma unroll
            for (int reg = 0; reg < 4; ++reg) {
                const int m_loc = wm * 32 + fm * 16 + lg * 4 + reg;  // row=(lane>>4)*4+reg
                const int n_loc = wn * 32 + fn * 16 + lr;            // col=lane&15
                yl[m_loc * 65 + n_loc] = acc[fm][fn][reg];
            }
    __syncthreads();

    int pcnt[4] = {0, 0, 0, 0};     // per-lane v-spike column partials
    u64 flagbits = 0;               // level-1 flags for this wave's 16 rows
    for (int r = 0; r < 16; ++r) {
        const int lrow = wv * 16 + r;
        const float y = yl[lrow * 65 + lane];
        float v = 0.f;
        int sp[4];
#pragma unroll
        for (int t = 0; t < 4; ++t) {
            v = v + (y - v) * 0.5f;           // decay_input charge, tau=2
            const int s = (v - 1.0f >= 0.f) ? 1 : 0;
            v = s ? 0.f : v;                  // hard reset
            sp[t] = s;
            pcnt[t] += s;
        }
        const int grow = bx * 64 + lrow;
        const int bb = grow >> 10;
        const int ss = grow & 1023;
        u64* dst = bits + (((size_t)(mat * 4) * 2 + bb) * 8 + h) * 1024 + ss;
        u64 mskarr[4];
#pragma unroll
        for (int t = 0; t < 4; ++t) {
            const u64 msk = __ballot(sp[t]);
            mskarr[t] = msk;
            if (lane == 0) dst[(size_t)t * (2 * 8 * 1024)] = msk;
        }
        if (mat == 0) {             // level-1 screen (same recurrence as attn)
            const int cc0 = (int)__popcll(mskarr[0]);
            const int cc1 = (int)__popcll(mskarr[1]);
            const int cc2 = (int)__popcll(mskarr[2]);
            const int cc3 = (int)__popcll(mskarr[3]);
            unsigned B = (unsigned)(cc0 << 2);
            unsigned mB = B;
            B = (B >> 1) + (unsigned)(cc1 << 2); mB = max(mB, B);
            B = (B >> 1) + (unsigned)(cc2 << 2); mB = max(mB, B);
            B = (B >> 1) + (unsigned)(cc3 << 2); mB = max(mB, B);
            if (mB >= 64u) flagbits |= (1ull << lrow);
        }
    }
    if (mat == 2) {                 // cs accumulation (device-scope, exact)
        const int bb = (bx * 64) >> 10;
        const int bh = bb * 8 + h;
#pragma unroll
        for (int t = 0; t < 4; ++t)
            atomicAdd(&csbuf[bh * 256 + t * 64 + lane], (unsigned)pcnt[t]);
    }
    if (mat == 0 && lane == 0 && flagbits) {
        const int bb = (bx * 64) >> 10;
        const int bh = bb * 8 + h;
        atomicOr(&flags[bh * 16 + (bx & 15)], flagbits);
    }
}

// ---------------- Kernel B10: flag-gated attn (R15 verbatim).
__global__ __launch_bounds__(256) void spike_attn10(
    const u64* __restrict__ bits,
    const unsigned* __restrict__ csbuf,
    const u64* __restrict__ flags,
    float* __restrict__ out)
{
    __shared__ u64 kb_s[4][1024];   // 32 KiB

    const int lane = threadIdx.x & 63;
    const int wave = RFL((int)(threadIdx.x >> 6));
    const int rt = blockIdx.x;   // 64 tiles of 16 rows
    const int h  = blockIdx.y;
    const int b  = blockIdx.z;

    const int bh = b * 8 + h;
    const u64* __restrict__ qb = bits + (size_t)bh * 1024;         // + t*16384
    const u64* __restrict__ kb = bits + (size_t)(64 + bh) * 1024;  // + t*16384
    const u64* __restrict__ vb = bits + (size_t)(128 + bh) * 1024; // + t*16384

    {
        const u64* __restrict__ srcT = kb + (size_t)wave * 16384;
#pragma unroll
        for (int i = 0; i < 8; ++i)
            gload_lds16(srcT + i * 128 + lane * 2, &kb_s[wave][i * 128]);
    }

    int cs[4];
#pragma unroll
    for (int t = 0; t < 4; ++t)
        cs[t] = (int)csbuf[bh * 256 + t * 64 + lane];
    const float base = (float)(cs[0] + cs[1] + cs[2] + cs[3]) * (1.0f / 4096.0f);

    const int s0 = rt * 16 + wave * 4;      // 4 rows per wave
    const u64 flagw = flags[bh * 16 + (s0 >> 6)];

    __syncthreads();   // kb_s ready

    const float E1 = 0.36787944117144233f;  // expf(-1)

#pragma unroll
    for (int r = 0; r < 4; ++r) {
        const int s = s0 + r;
        float o = base;
        if ((flagw >> (s & 63)) & 1ull) {   // wave-uniform; ~15-20% of rows
            const u64 q0 = qb[s];
            const u64 q1 = qb[16384 + s];
            const u64 q2 = qb[32768 + s];
            const u64 q3 = qb[49152 + s];
            int found = 0;
            for (int w = 0; w < 16; ++w) {
                const int ko = (w << 6) + lane;
                const int pc0 = (int)__popcll(kb_s[0][ko] & q0);
                const int pc1 = (int)__popcll(kb_s[1][ko] & q1);
                const int pc2 = (int)__popcll(kb_s[2][ko] & q2);
                const int pc3 = (int)__popcll(kb_s[3][ko] & q3);
                found = max(found, max(max(pc0, pc1), max(pc2, pc3)));
            }
            const u64 any = __ballot(found >= 9);
            if (any) {              // wave-uniform; rare
                int msum[4] = {0, 0, 0, 0}, n11[4] = {0, 0, 0, 0};
                for (int w = 0; w < 16; ++w) {
                    const int ko = (w << 6) + lane;
                    const int pcs[4] = {
                        (int)__popcll(kb_s[0][ko] & q0),
                        (int)__popcll(kb_s[1][ko] & q1),
                        (int)__popcll(kb_s[2][ko] & q2),
                        (int)__popcll(kb_s[3][ko] & q3)};
                    unsigned u = 0;
#pragma unroll
                    for (int t = 0; t < 4; ++t) {
                        u = (u >> 1) + (unsigned)(pcs[t] << 2);  // 64ths; exact
                        const int spk = (u >= 64u) ? 1 : 0;
                        const u64 msk = __ballot(spk);
                        u = spk ? 0u : u;
                        msum[t] += (int)__popcll(msk);
                        u64 m = msk;
                        while (m) {     // bit-scan: 1 broadcast v-load/spike
                            const int j = (int)__builtin_ctzll(m);
                            m &= m - 1;
                            const u64 vw = vb[t * 16384 + (w << 6) + j];
                            n11[t] += (int)((vw >> lane) & 1ull);
                        }
                    }
                }
                o = 0.f;
#pragma unroll
                for (int t = 0; t < 4; ++t) {
                    const float mf = (float)msum[t];
                    const float Z  = mf + (1024.f - mf) * E1;
                    const float p1 = 1.0f / Z;
                    const float p0 = E1 / Z;
                    o += p0 * (float)cs[t] + (p1 - p0) * (float)n11[t];
                }
                o *= 0.25f;
            }
        }
        out[((size_t)b * 1024 + s) * 512 + (h << 6) + lane] = o;
    }
}

extern "C" void kernel_launch(void* const* d_in, const int* in_sizes, int n_in,
                              void* d_out, int out_size, void* d_ws, size_t ws_size,
                              hipStream_t stream) {
    const float* x  = (const float*)d_in[0];
    const float* Wq = (const float*)d_in[1];
    const float* Wk = (const float*)d_in[2];
    const float* Wv = (const float*)d_in[3];
    float* out = (float*)d_out;

    u64* bits = (u64*)d_ws;                          // 1.5 MiB (+0.5 unused)
    _Float16* xh = (_Float16*)((char*)d_ws + (2u << 20));
    _Float16* xl = xh + (size_t)2048 * 512;
    _Float16* wh = xl + (size_t)2048 * 512;
    unsigned* csbuf = (unsigned*)(wh + (size_t)1536 * 512);  // 16 KiB
    u64* flags = (u64*)(csbuf + 4096);                       // 2 KiB

    cvt_split16<<<dim3(897), 256, 0, stream>>>(x, Wq, Wk, Wv, xh, xl, wh, csbuf);
    gemm_mfma_lif_pack6<<<dim3(24, 32), 256, 0, stream>>>(xh, xl, wh, bits, csbuf, flags);
    spike_attn10<<<dim3(64, 8, 2), 256, 0, stream>>>(bits, csbuf, flags, out);
}